// Round 2
// baseline (196.872 us; speedup 1.0000x reference)
//
#include <hip/hip_runtime.h>
#include <hip/hip_bf16.h>

using u16 = unsigned short;
typedef __bf16 bf16x8 __attribute__((ext_vector_type(8)));
typedef float f32x4 __attribute__((ext_vector_type(4)));

#define N_B   16
#define L_S   512
#define D_F   256
#define T_MEL 4096
#define M_TOT (N_B * L_S)
#define OUT_ELEMS ((size_t)N_B * T_MEL * D_F)   // fp32 elems
#define H1_ELEMS  ((size_t)M_TOT * D_F)         // bf16 elems
#define WP_ELEMS  (24 * 8192)                   // packed weight elems per conv
#define TBLK 128

__device__ __forceinline__ u16 f2bf(float f) {
  __hip_bfloat16 h = __float2bfloat16(f);
  return *(u16*)&h;
}

// ---------------------------------------------------------------------------
// Weight pack only: wp[s][f][ki] = w[f][(s&7)*32+ki][s>>3]  (proven indexing).
// ---------------------------------------------------------------------------
__global__ __launch_bounds__(256)
void pack_kernel(const float* __restrict__ w1, const float* __restrict__ w2,
                 u16* __restrict__ wp1, u16* __restrict__ wp2) {
  int o   = (int)blockIdx.x * 256 + (int)threadIdx.x;   // 0..196607
  int s   = o >> 13;
  int rem = o & 8191;
  int f   = rem >> 5;
  int ki  = rem & 31;
  int d   = ((s & 7) << 5) + ki;
  int tap = s >> 3;
  int src = f * 768 + d * 3 + tap;
  wp1[o] = f2bf(w1[src]);
  wp2[o] = f2bf(w2[src]);
}

// ---------------------------------------------------------------------------
// Fused conv1d(K=3) im2col GEMM + bias + LN + ReLU — round-0 dataflow
// (256 threads, 4 waves, 32-row tiles, 24 K-steps), with TWO changes:
//  1. LDS tiles are 64B-row, 16B-slot XOR-swizzled (slot ^= row&3) on both
//     write and read. The old 40-u16 pad (80B = 20-dword stride) put 8 lanes
//     on the same bank group for every ds_read_b128/ds_write (8-way ≈ 2.94x,
//     m136). Swizzled layout gives every LDS instruction a balanced 1KB
//     footprint (<=2-way = free).
//  2. Stage 1 reads fp32 x directly, converting in-register (bit-identical
//     to the old cast pass; validated in round 1, absmax unchanged).
// ---------------------------------------------------------------------------
template<int STAGE>
__global__ __launch_bounds__(256)
void conv_ln_kernel(const float* __restrict__ Xf,  // stage-1 input (fp32)
                    const u16*  __restrict__ Xh,   // stage-2 input (bf16)
                    const u16*  __restrict__ Wp,
                    const float* __restrict__ cb,  const float* __restrict__ lgm,
                    const float* __restrict__ lbt, const float* __restrict__ lw,
                    const float* __restrict__ lb,  u16* __restrict__ Hout,
                    float* __restrict__ dpo)
{
  // 64B rows (32 u16), no pad; swizzle: physical 16B slot = slot ^ (row&3)
  __shared__ __align__(16) u16 As[32 * 32];
  __shared__ __align__(16) u16 Bs[256 * 32];
  __shared__ float sBias[256], sG[256], sB[256], sLw[256];
  __shared__ float redS[2][32], redQ[2][32];

  const int t = threadIdx.x;
  sBias[t] = cb[t];
  sG[t]    = lgm[t];
  sB[t]    = lbt[t];
  if (STAGE == 2) sLw[t] = lw[t];

  const int m0   = blockIdx.x * 32;
  const int n    = m0 >> 9;
  const int l0   = m0 & 511;
  const int wave = t >> 6, lane = t & 63;
  const int wr   = (wave & 1) * 16;
  const int wc   = (wave >> 1) * 128;
  const int p    = lane & 15, q = lane >> 4;

  f32x4 acc[8];
  #pragma unroll
  for (int i = 0; i < 8; i++) acc[i] = (f32x4){0.f, 0.f, 0.f, 0.f};

  // A loaders: 256 thr, 8 thr/row, 4 u16 (8B) each: row ar, byte (t&7)*8
  const int ar = t >> 3, ak = (t & 7) * 4;
  // A write address (swizzled): slot=(t&7)>>1, half=(t&7)&1
  const int aw_byte = ar * 64 + (((((t & 7) >> 1) ^ (ar & 3)) << 4) | (((t & 7) & 1) << 3));
  // B loaders: 4 thr/row, 16B each: rows bf0+i*64, slot (t&3)
  const int bc = (t & 3) * 8, bf0 = t >> 2;

  uint2 pa;
  uint4 pb[4];
  auto LA = [&](int s) {
    const int tap = s >> 3, dbase = (s & 7) * 32;
    const int lsrc = l0 + ar + tap - 1;
    if (lsrc >= 0 && lsrc < L_S) {
      if (STAGE == 1) {
        float4 v = *(const float4*)(Xf + (((size_t)((n << 9) + lsrc)) << 8) + dbase + ak);
        u16 a = f2bf(v.x), b = f2bf(v.y), c = f2bf(v.z), d = f2bf(v.w);
        pa.x = (unsigned)a | ((unsigned)b << 16);
        pa.y = (unsigned)c | ((unsigned)d << 16);
      } else {
        pa = *(const uint2*)(Xh + (((size_t)((n << 9) + lsrc)) << 8) + dbase + ak);
      }
    } else { pa.x = 0u; pa.y = 0u; }
  };
  auto LB = [&](int s) {
    const u16* src = Wp + ((size_t)s << 13) + bc;
    #pragma unroll
    for (int i = 0; i < 4; i++)
      pb[i] = *(const uint4*)(src + ((bf0 + (i << 6)) << 5));
  };
  LA(0); LB(0);

  for (int s = 0; s < 24; s++) {
    __syncthreads();
    *(uint2*)((char*)As + aw_byte) = pa;
    #pragma unroll
    for (int i = 0; i < 4; i++) {
      int r = bf0 + (i << 6);
      *(uint4*)((char*)Bs + r * 64 + ((((t & 3) ^ (r & 3)) << 4))) = pb[i];
    }
    if (s < 23) { LA(s + 1); LB(s + 1); }
    __syncthreads();
    {
      int rA = wr + p;
      bf16x8 af = *(const bf16x8*)((const char*)As + rA * 64 + ((q ^ (rA & 3)) << 4));
      #pragma unroll
      for (int ct = 0; ct < 8; ct++) {
        int rB = wc + ct * 16 + p;
        bf16x8 bfr = *(const bf16x8*)((const char*)Bs + rB * 64 + ((q ^ (rB & 3)) << 4));
        acc[ct] = __builtin_amdgcn_mfma_f32_16x16x32_bf16(af, bfr, acc[ct], 0, 0, 0);
      }
    }
  }

  // ---- bias + per-row sum / sumsq ----
  float s0[4] = {0,0,0,0}, s1[4] = {0,0,0,0};
  #pragma unroll
  for (int ct = 0; ct < 8; ct++) {
    float bias = sBias[wc + ct * 16 + p];
    #pragma unroll
    for (int j = 0; j < 4; j++) {
      float v = acc[ct][j] + bias;
      acc[ct][j] = v;
      s0[j] += v;
      s1[j] += v * v;
    }
  }
  #pragma unroll
  for (int m = 1; m <= 8; m <<= 1) {
    #pragma unroll
    for (int j = 0; j < 4; j++) {
      s0[j] += __shfl_xor(s0[j], m);
      s1[j] += __shfl_xor(s1[j], m);
    }
  }
  const int half = wave >> 1;
  if (p == 0) {
    #pragma unroll
    for (int j = 0; j < 4; j++) {
      redS[half][wr + q * 4 + j] = s0[j];
      redQ[half][wr + q * 4 + j] = s1[j];
    }
  }
  __syncthreads();
  float mean[4], rstd[4];
  #pragma unroll
  for (int j = 0; j < 4; j++) {
    int r = wr + q * 4 + j;
    float S = redS[0][r] + redS[1][r];
    float Q = redQ[0][r] + redQ[1][r];
    float mu  = S * (1.0f / 256.0f);
    float var = Q * (1.0f / 256.0f) - mu * mu;
    mean[j] = mu;
    rstd[j] = rsqrtf(var + 1e-5f);
  }

  if (STAGE == 1) {
    #pragma unroll
    for (int ct = 0; ct < 8; ct++) {
      int c = wc + ct * 16 + p;
      float gg = sG[c], bb = sB[c];
      #pragma unroll
      for (int j = 0; j < 4; j++) {
        float v = (acc[ct][j] - mean[j]) * rstd[j] * gg + bb;
        v = fmaxf(v, 0.0f);
        Hout[(size_t)(m0 + wr + q * 4 + j) * 256 + c] = f2bf(v);
      }
    }
  } else {
    float ls[4] = {0,0,0,0};
    #pragma unroll
    for (int ct = 0; ct < 8; ct++) {
      int c = wc + ct * 16 + p;
      float gg = sG[c], bb = sB[c], ww = sLw[c];
      #pragma unroll
      for (int j = 0; j < 4; j++) {
        float v = (acc[ct][j] - mean[j]) * rstd[j] * gg + bb;
        v = fmaxf(v, 0.0f);
        ls[j] += v * ww;
      }
    }
    #pragma unroll
    for (int m = 1; m <= 8; m <<= 1) {
      #pragma unroll
      for (int j = 0; j < 4; j++) ls[j] += __shfl_xor(ls[j], m);
    }
    __syncthreads();
    if (p == 0) {
      #pragma unroll
      for (int j = 0; j < 4; j++) redS[half][wr + q * 4 + j] = ls[j];
    }
    __syncthreads();
    if (half == 0 && p == 0) {
      float lbf = lb[0];
      #pragma unroll
      for (int j = 0; j < 4; j++) {
        int r = wr + q * 4 + j;
        float dv = fmaxf(redS[0][r] + redS[1][r] + lbf, 0.0f);
        dpo[m0 + r] = dv;
      }
    }
  }
}

// ---------------------------------------------------------------------------
// Length-regulate (fp32): parallel Hillis-Steele scan + binary search.
// Round-0 verbatim (proven: output 0 bit-exact). Runs LAST (overwrites
// the scratch that lives in the out region).
// ---------------------------------------------------------------------------
__global__ __launch_bounds__(256)
void lr_kernel(const float* __restrict__ X, const int* __restrict__ tgt,
               float* __restrict__ out) {
  __shared__ int c[L_S];
  __shared__ int sidx[TBLK];
  const int t  = threadIdx.x;               // 0..255
  const int n  = blockIdx.x >> 5;           // 32 chunks per n
  const int t0 = (blockIdx.x & 31) * TBLK;

  c[t]       = tgt[n * L_S + t];
  c[t + 256] = tgt[n * L_S + t + 256];
  __syncthreads();
  for (int off = 1; off < L_S; off <<= 1) {
    int v0 = (t >= off) ? c[t - off] : 0;
    int i1 = t + 256;
    int v1 = (i1 >= off) ? c[i1 - off] : 0;
    __syncthreads();
    c[t]  += v0;
    c[i1] += v1;
    __syncthreads();
  }
  const int total = c[L_S - 1];
  if (t < TBLK) {
    int tt = t0 + t;
    int lo = 0, hi = L_S;
    while (lo < hi) {                       // upper_bound: first c[i] > tt
      int mid = (lo + hi) >> 1;
      if (c[mid] <= tt) lo = mid + 1; else hi = mid;
    }
    sidx[t] = (tt < total) ? lo : -1;
  }
  __syncthreads();

  #pragma unroll
  for (int i = 0; i < 32; i++) {
    int u   = t + i * 256;                  // 128 rows x 64 float4
    int dg  = u & 63;
    int tr  = u >> 6;
    int idx = sidx[tr];
    float4 v = make_float4(0.f, 0.f, 0.f, 0.f);
    if (idx >= 0)
      v = *(const float4*)(X + (((size_t)(n * L_S + idx)) << 8) + dg * 4);
    *(float4*)(out + (((size_t)(n * T_MEL + t0 + tr)) << 8) + dg * 4) = v;
  }
}

// ---------------------------------------------------------------------------
extern "C" void kernel_launch(void* const* d_in, const int* in_sizes, int n_in,
                              void* d_out, int out_size, void* d_ws, size_t ws_size,
                              hipStream_t stream) {
  (void)d_ws; (void)ws_size; (void)in_sizes; (void)n_in; (void)out_size;

  const float* x   = (const float*)d_in[0];
  const float* w1  = (const float*)d_in[1];
  const float* b1  = (const float*)d_in[2];
  const float* g1  = (const float*)d_in[3];
  const float* be1 = (const float*)d_in[4];
  const float* w2  = (const float*)d_in[5];
  const float* b2  = (const float*)d_in[6];
  const float* g2  = (const float*)d_in[7];
  const float* be2 = (const float*)d_in[8];
  const float* lw  = (const float*)d_in[9];
  const float* lb  = (const float*)d_in[10];
  const int*   tgt = (const int*)d_in[11];

  float* out = (float*)d_out;
  float* dpo = out + OUT_ELEMS;

  // bf16 scratch inside the fp32 output-0 region; overwritten by final LR.
  u16* h1  = (u16*)d_out;
  u16* wp1 = h1 + H1_ELEMS;
  u16* wp2 = wp1 + WP_ELEMS;

  pack_kernel<<<768, 256, 0, stream>>>(w1, w2, wp1, wp2);
  conv_ln_kernel<1><<<M_TOT / 32, 256, 0, stream>>>(
      x, nullptr, wp1, b1, g1, be1, nullptr, nullptr, h1, nullptr);
  conv_ln_kernel<2><<<M_TOT / 32, 256, 0, stream>>>(
      nullptr, h1, wp2, b2, g2, be2, lw, lb, nullptr, dpo);
  lr_kernel<<<N_B * (T_MEL / TBLK), 256, 0, stream>>>(x, tgt, out);
}

// Round 3
// 154.778 us; speedup vs baseline: 1.2720x; 1.2720x over previous
//
#include <hip/hip_runtime.h>
#include <hip/hip_bf16.h>

using u16 = unsigned short;
typedef __bf16 bf16x8 __attribute__((ext_vector_type(8)));
typedef float f32x4 __attribute__((ext_vector_type(4)));

#define N_B   16
#define L_S   512
#define D_F   256
#define T_MEL 4096
#define M_TOT (N_B * L_S)
#define OUT_ELEMS ((size_t)N_B * T_MEL * D_F)   // fp32 elems
#define H1_ELEMS  ((size_t)M_TOT * D_F)         // bf16 elems
#define WP_ELEMS  (24 * 8192)                   // packed weight elems per conv
#define TBLK 128

__device__ __forceinline__ u16 f2bf(float f) {
  __hip_bfloat16 h = __float2bfloat16(f);
  return *(u16*)&h;
}

__device__ __forceinline__ bf16x8 bf8_zero() {
  uint4 z = make_uint4(0u, 0u, 0u, 0u);
  bf16x8 r;
  __builtin_memcpy(&r, &z, 16);
  return r;
}

__device__ __forceinline__ bf16x8 pack8(float4 v0, float4 v1) {
  union { bf16x8 h; u16 u[8]; } r;
  r.u[0] = f2bf(v0.x); r.u[1] = f2bf(v0.y); r.u[2] = f2bf(v0.z); r.u[3] = f2bf(v0.w);
  r.u[4] = f2bf(v1.x); r.u[5] = f2bf(v1.y); r.u[6] = f2bf(v1.z); r.u[7] = f2bf(v1.w);
  return r.h;
}

// ---------------------------------------------------------------------------
// Weight pack: wp[s][f][ki] = w[f][(s&7)*32+ki][s>>3]  (proven indexing).
// ---------------------------------------------------------------------------
__global__ __launch_bounds__(256)
void pack_kernel(const float* __restrict__ w1, const float* __restrict__ w2,
                 u16* __restrict__ wp1, u16* __restrict__ wp2) {
  int o   = (int)blockIdx.x * 256 + (int)threadIdx.x;   // 0..196607
  int s   = o >> 13;
  int rem = o & 8191;
  int f   = rem >> 5;
  int ki  = rem & 31;
  int d   = ((s & 7) << 5) + ki;
  int tap = s >> 3;
  int src = f * 768 + d * 3 + tap;
  wp1[o] = f2bf(w1[src]);
  wp2[o] = f2bf(w2[src]);
}

// ---------------------------------------------------------------------------
// Fused conv1d(K=3) im2col GEMM + bias + LN + ReLU — NO-LDS-STAGING version.
// Rationale (round-2 counters): conv was 55us with MfmaUtil 2%, VALUBusy 4%,
// HBM 3% — pure latency stall from the barrier-lockstep LDS pipeline at
// 1 wave/SIMD. Wp (384KB) and X (8MB) are L2-resident; staging them in LDS
// bought nothing and forced vmcnt(0)+barrier drains every K-step.
// New structure: 512 blocks x 256 thr (16-row x 256-col tiles, 2 blocks/CU,
// 2 waves/SIMD at independent phases). Each wave double-buffers its A-frag +
// 4 B-frags in REGISTERS straight from global; zero barriers in the K-loop,
// so next-step loads stay in flight across the MFMAs (counted-vmcnt pattern).
// LDS holds only the 4.5KB LN reduction scratch. Epilogue math proven.
// ---------------------------------------------------------------------------
template<int STAGE>
__global__ __launch_bounds__(256)
void conv_ln_kernel(const float* __restrict__ Xf,  // stage-1 input (fp32)
                    const u16*  __restrict__ Xh,   // stage-2 input (bf16)
                    const u16*  __restrict__ Wp,
                    const float* __restrict__ cb,  const float* __restrict__ lgm,
                    const float* __restrict__ lbt, const float* __restrict__ lw,
                    const float* __restrict__ lb,  u16* __restrict__ Hout,
                    float* __restrict__ dpo)
{
  __shared__ float sBias[256], sG[256], sB[256], sLw[256];
  __shared__ float redS[4][16], redQ[4][16];

  const int t = threadIdx.x;
  sBias[t] = cb[t];
  sG[t]    = lgm[t];
  sB[t]    = lbt[t];
  if (STAGE == 2) sLw[t] = lw[t];
  __syncthreads();                       // smem params ready; no more barriers
                                         // until the epilogue reduction.

  const int m0   = (int)blockIdx.x * 16; // 16-row tile
  const int n    = m0 >> 9;
  const int l0   = m0 & 511;
  const int wave = t >> 6, lane = t & 63;
  const int wc   = wave * 64;            // this wave's 64-col slice
  const int p    = lane & 15, q = lane >> 4;

  f32x4 acc[4];
  #pragma unroll
  for (int i = 0; i < 4; i++) acc[i] = (f32x4){0.f, 0.f, 0.f, 0.f};

  // ---- direct-from-global fragment loaders (double-buffered in regs) ----
  auto LDA = [&](int s, bf16x8 &dst) {
    const int tap = s >> 3, dbase = (s & 7) << 5;
    const int lsrc = l0 + p + tap - 1;
    const bool ok = (unsigned)lsrc < 512u;
    const int lc = ok ? lsrc : 0;
    if (STAGE == 1) {
      const float* src = Xf + (((size_t)((n << 9) + lc)) << 8) + dbase + (q << 3);
      float4 v0 = *(const float4*)(src);
      float4 v1 = *(const float4*)(src + 4);
      dst = pack8(v0, v1);
    } else {
      dst = *(const bf16x8*)(Xh + (((size_t)((n << 9) + lc)) << 8) + dbase + (q << 3));
    }
    if (!ok) dst = bf8_zero();
  };
  auto LDB = [&](int s, bf16x8 (&b)[4]) {
    const u16* src = Wp + ((size_t)s << 13) + (size_t)p * 32 + (q << 3);
    #pragma unroll
    for (int ct = 0; ct < 4; ct++)
      b[ct] = *(const bf16x8*)(src + ((wc + ct * 16) << 5));
  };

  bf16x8 aA, aB, bA[4], bB[4];
  LDA(0, aA); LDB(0, bA);

  for (int s2 = 0; s2 < 24; s2 += 2) {
    // issue loads for s2+1 while computing s2
    if (s2 + 1 < 24) { LDA(s2 + 1, aB); LDB(s2 + 1, bB); }
    #pragma unroll
    for (int ct = 0; ct < 4; ct++)
      acc[ct] = __builtin_amdgcn_mfma_f32_16x16x32_bf16(aA, bA[ct], acc[ct], 0, 0, 0);
    // issue loads for s2+2 while computing s2+1
    if (s2 + 2 < 24) { LDA(s2 + 2, aA); LDB(s2 + 2, bA); }
    #pragma unroll
    for (int ct = 0; ct < 4; ct++)
      acc[ct] = __builtin_amdgcn_mfma_f32_16x16x32_bf16(aB, bB[ct], acc[ct], 0, 0, 0);
  }

  // ---- bias + per-row sum / sumsq over this wave's 64 cols ----
  // lane(p,q), acc[ct][j] = C[row q*4+j][col wc+ct*16+p]
  float s0[4] = {0,0,0,0}, s1[4] = {0,0,0,0};
  #pragma unroll
  for (int ct = 0; ct < 4; ct++) {
    float bias = sBias[wc + ct * 16 + p];
    #pragma unroll
    for (int j = 0; j < 4; j++) {
      float v = acc[ct][j] + bias;
      acc[ct][j] = v;
      s0[j] += v;
      s1[j] += v * v;
    }
  }
  #pragma unroll
  for (int m = 1; m <= 8; m <<= 1) {     // reduce across the 16 p-lanes
    #pragma unroll
    for (int j = 0; j < 4; j++) {
      s0[j] += __shfl_xor(s0[j], m);
      s1[j] += __shfl_xor(s1[j], m);
    }
  }
  if (p == 0) {
    #pragma unroll
    for (int j = 0; j < 4; j++) {
      redS[wave][q * 4 + j] = s0[j];
      redQ[wave][q * 4 + j] = s1[j];
    }
  }
  __syncthreads();
  float mean[4], rstd[4];
  #pragma unroll
  for (int j = 0; j < 4; j++) {
    int r = q * 4 + j;
    float S = redS[0][r] + redS[1][r] + redS[2][r] + redS[3][r];
    float Q = redQ[0][r] + redQ[1][r] + redQ[2][r] + redQ[3][r];
    float mu  = S * (1.0f / 256.0f);
    float var = Q * (1.0f / 256.0f) - mu * mu;
    mean[j] = mu;
    rstd[j] = rsqrtf(var + 1e-5f);
  }

  if (STAGE == 1) {
    #pragma unroll
    for (int ct = 0; ct < 4; ct++) {
      int c = wc + ct * 16 + p;
      float gg = sG[c], bb = sB[c];
      #pragma unroll
      for (int j = 0; j < 4; j++) {
        float v = (acc[ct][j] - mean[j]) * rstd[j] * gg + bb;
        v = fmaxf(v, 0.0f);
        Hout[(size_t)(m0 + q * 4 + j) * 256 + c] = f2bf(v);
      }
    }
  } else {
    float ls[4] = {0,0,0,0};
    #pragma unroll
    for (int ct = 0; ct < 4; ct++) {
      int c = wc + ct * 16 + p;
      float gg = sG[c], bb = sB[c], ww = sLw[c];
      #pragma unroll
      for (int j = 0; j < 4; j++) {
        float v = (acc[ct][j] - mean[j]) * rstd[j] * gg + bb;
        v = fmaxf(v, 0.0f);
        ls[j] += v * ww;
      }
    }
    #pragma unroll
    for (int m = 1; m <= 8; m <<= 1) {
      #pragma unroll
      for (int j = 0; j < 4; j++) ls[j] += __shfl_xor(ls[j], m);
    }
    __syncthreads();                     // redS free for reuse
    if (p == 0) {
      #pragma unroll
      for (int j = 0; j < 4; j++) redS[wave][q * 4 + j] = ls[j];
    }
    __syncthreads();
    if (t < 16) {
      float dv = fmaxf(redS[0][t] + redS[1][t] + redS[2][t] + redS[3][t] + lb[0], 0.0f);
      dpo[m0 + t] = dv;
    }
  }
}

// ---------------------------------------------------------------------------
// Length-regulate (fp32): parallel Hillis-Steele scan + binary search.
// Proven verbatim (output 0 bit-exact). Runs LAST (overwrites scratch in out).
// ---------------------------------------------------------------------------
__global__ __launch_bounds__(256)
void lr_kernel(const float* __restrict__ X, const int* __restrict__ tgt,
               float* __restrict__ out) {
  __shared__ int c[L_S];
  __shared__ int sidx[TBLK];
  const int t  = threadIdx.x;               // 0..255
  const int n  = blockIdx.x >> 5;           // 32 chunks per n
  const int t0 = (blockIdx.x & 31) * TBLK;

  c[t]       = tgt[n * L_S + t];
  c[t + 256] = tgt[n * L_S + t + 256];
  __syncthreads();
  for (int off = 1; off < L_S; off <<= 1) {
    int v0 = (t >= off) ? c[t - off] : 0;
    int i1 = t + 256;
    int v1 = (i1 >= off) ? c[i1 - off] : 0;
    __syncthreads();
    c[t]  += v0;
    c[i1] += v1;
    __syncthreads();
  }
  const int total = c[L_S - 1];
  if (t < TBLK) {
    int tt = t0 + t;
    int lo = 0, hi = L_S;
    while (lo < hi) {                       // upper_bound: first c[i] > tt
      int mid = (lo + hi) >> 1;
      if (c[mid] <= tt) lo = mid + 1; else hi = mid;
    }
    sidx[t] = (tt < total) ? lo : -1;
  }
  __syncthreads();

  #pragma unroll
  for (int i = 0; i < 32; i++) {
    int u   = t + i * 256;                  // 128 rows x 64 float4
    int dg  = u & 63;
    int tr  = u >> 6;
    int idx = sidx[tr];
    float4 v = make_float4(0.f, 0.f, 0.f, 0.f);
    if (idx >= 0)
      v = *(const float4*)(X + (((size_t)(n * L_S + idx)) << 8) + dg * 4);
    *(float4*)(out + (((size_t)(n * T_MEL + t0 + tr)) << 8) + dg * 4) = v;
  }
}

// ---------------------------------------------------------------------------
extern "C" void kernel_launch(void* const* d_in, const int* in_sizes, int n_in,
                              void* d_out, int out_size, void* d_ws, size_t ws_size,
                              hipStream_t stream) {
  (void)d_ws; (void)ws_size; (void)in_sizes; (void)n_in; (void)out_size;

  const float* x   = (const float*)d_in[0];
  const float* w1  = (const float*)d_in[1];
  const float* b1  = (const float*)d_in[2];
  const float* g1  = (const float*)d_in[3];
  const float* be1 = (const float*)d_in[4];
  const float* w2  = (const float*)d_in[5];
  const float* b2  = (const float*)d_in[6];
  const float* g2  = (const float*)d_in[7];
  const float* be2 = (const float*)d_in[8];
  const float* lw  = (const float*)d_in[9];
  const float* lb  = (const float*)d_in[10];
  const int*   tgt = (const int*)d_in[11];

  float* out = (float*)d_out;
  float* dpo = out + OUT_ELEMS;

  // bf16 scratch inside the fp32 output-0 region; overwritten by final LR.
  u16* h1  = (u16*)d_out;
  u16* wp1 = h1 + H1_ELEMS;
  u16* wp2 = wp1 + WP_ELEMS;

  pack_kernel<<<768, 256, 0, stream>>>(w1, w2, wp1, wp2);
  conv_ln_kernel<1><<<M_TOT / 16, 256, 0, stream>>>(
      x, nullptr, wp1, b1, g1, be1, nullptr, nullptr, h1, nullptr);
  conv_ln_kernel<2><<<M_TOT / 16, 256, 0, stream>>>(
      nullptr, h1, wp2, b2, g2, be2, lw, lb, nullptr, dpo);
  lr_kernel<<<N_B * (T_MEL / TBLK), 256, 0, stream>>>(x, tgt, out);
}